// Round 10
// baseline (205.135 us; speedup 1.0000x reference)
//
#include <hip/hip_runtime.h>

typedef unsigned short u16;
typedef __attribute__((ext_vector_type(8))) __bf16 bf16x8;
typedef __attribute__((ext_vector_type(8))) short  short8;
typedef __attribute__((ext_vector_type(4))) short  short4v;
typedef __attribute__((ext_vector_type(4))) float  floatx4;
typedef __attribute__((ext_vector_type(4))) int    intx4;
typedef __attribute__((ext_vector_type(2))) int    intx2;

constexpr int Bc = 2, Sc = 2048, Ec = 1024, Hc = 16, Dc = 64;
constexpr int Mc = Bc * Sc;  // 4096

#define QSCALE  0.18033688011112042f  // 0.125 * log2(e): scores in exp2 domain

__device__ __forceinline__ u16 f2b(float f) {          // RTNE
  union { float f; unsigned u; } c; c.f = f;
  unsigned u = c.u;
  return (u16)((u + 0x7fffu + ((u >> 16) & 1u)) >> 16);
}
__device__ __forceinline__ short8 ld8(const u16* p) { return *(const short8*)p; }

// packed f32x2 -> bf16x2 (RTNE), 1 VALU op [T12 recipe; no builtin on gfx950]
__device__ __forceinline__ int cvt_pk(float lo, float hi) {
  int r;
  asm("v_cvt_pk_bf16_f32 %0, %1, %2" : "=v"(r) : "v"(lo), "v"(hi));
  return r;
}

__device__ __forceinline__ floatx4 mfma16(short8 a, short8 b, floatx4 c) {
  return __builtin_amdgcn_mfma_f32_16x16x32_bf16(
      __builtin_bit_cast(bf16x8, a), __builtin_bit_cast(bf16x8, b), c, 0, 0, 0);
}

// async global->LDS, 16B/lane; LDS ptr is the wave-uniform base (HW deposits
// at base + lane*16). [m97/m104 pattern]
__device__ __forceinline__ void async16(const u16* g, u16* l) {
  __builtin_amdgcn_global_load_lds(
      (const __attribute__((address_space(1))) void*)g,
      (__attribute__((address_space(3))) void*)l, 16, 0, 0);
}

// ---------------------------------------------------------------------------
// fp32 -> bf16 bulk convert: dst = [xb (4Mi) | Wq | Wk | Wv | Wo (1Mi each)].
// ---------------------------------------------------------------------------
__global__ __launch_bounds__(256) void cvt_kernel(
    const float* __restrict__ x,  const float* __restrict__ Wq,
    const float* __restrict__ Wk, const float* __restrict__ Wv,
    const float* __restrict__ Wo, u16* __restrict__ dst) {
  const size_t i = ((size_t)blockIdx.x * 256 + threadIdx.x) * 4;
  const int seg = (int)(i >> 20);
  const float* src;
  size_t off;
  if (seg < 4)       { src = x;  off = i; }
  else if (seg == 4) { src = Wq; off = i - ((size_t)4 << 20); }
  else if (seg == 5) { src = Wk; off = i - ((size_t)5 << 20); }
  else if (seg == 6) { src = Wv; off = i - ((size_t)6 << 20); }
  else               { src = Wo; off = i - ((size_t)7 << 20); }
  floatx4 v = *(const floatx4*)(src + off);
  intx2 o;
  o[0] = cvt_pk(v[0], v[1]);
  o[1] = cvt_pk(v[2], v[3]);
  *(intx2*)(dst + i) = o;
}

// ---------------------------------------------------------------------------
// 128x128 GEMM mainloop v5 (r7-verified): counted-vmcnt double-buffer.
// ---------------------------------------------------------------------------
__device__ __forceinline__ void gemm128d(
    const u16* __restrict__ A, const u16* __restrict__ B, int K,
    int m0, int n0, u16* As, u16* Bs, floatx4 acc[4][4]) {
  const int t = threadIdx.x;
  const int w = t >> 6, lane = t & 63;
  const int wm = w & 1, wn = w >> 1;
  const int quad = lane >> 4, l16 = lane & 15;
  const int r = t >> 2;                            // staging row 0..63
  const int c = ((t & 3) ^ ((t >> 3) & 3)) * 8;    // swizzled source block
  const int rs = (quad ^ ((l16 >> 1) & 3)) * 8;    // read-side slot

  const u16* ap0 = A + (size_t)(m0 + r) * K + c;
  const u16* ap1 = A + (size_t)(m0 + 64 + r) * K + c;
  const u16* bp0 = B + (size_t)(n0 + r) * K + c;
  const u16* bp1 = B + (size_t)(n0 + 64 + r) * K + c;
  u16* const al0 = As + w * 512;                   // wave-uniform LDS bases
  u16* const al1 = As + 2048 + w * 512;
  u16* const bl0 = Bs + w * 512;
  u16* const bl1 = Bs + 2048 + w * 512;

#pragma unroll
  for (int i = 0; i < 4; ++i)
#pragma unroll
    for (int j = 0; j < 4; ++j) acc[i][j] = 0.f;

  // prologue: tile 0 -> buffer 0
  async16(ap0, al0);
  async16(ap1, al1);
  async16(bp0, bl0);
  async16(bp1, bl1);

  int cur = 0;
  for (int k0 = 0; k0 < K; k0 += 32) {
    if (k0 + 32 < K) {
      const int nb = cur ^ 1;
      async16(ap0 + k0 + 32, al0 + nb * 4096);
      async16(ap1 + k0 + 32, al1 + nb * 4096);
      async16(bp0 + k0 + 32, bl0 + nb * 4096);
      async16(bp1 + k0 + 32, bl1 + nb * 4096);
      __builtin_amdgcn_sched_barrier(0);           // stages precede the wait
      asm volatile("s_waitcnt vmcnt(4)");          // prev tile done; 4 in flight
    } else {
      asm volatile("s_waitcnt vmcnt(0)");          // epilogue drain
    }
    __builtin_amdgcn_s_barrier();                  // all waves' deposits visible
    __builtin_amdgcn_sched_barrier(0);             // no ds_read hoists above

    short8 af[4], bfr[4];
#pragma unroll
    for (int i = 0; i < 4; ++i)
      af[i]  = *(const short8*)(As + cur * 4096 +
                                (wm * 64 + i * 16 + l16) * 32 + rs);
#pragma unroll
    for (int j = 0; j < 4; ++j)
      bfr[j] = *(const short8*)(Bs + cur * 4096 +
                                (wn * 64 + j * 16 + l16) * 32 + rs);
#pragma unroll
    for (int i = 0; i < 4; ++i)
#pragma unroll
      for (int j = 0; j < 4; ++j)
        acc[i][j] = mfma16(af[i], bfr[j], acc[i][j]);

    __builtin_amdgcn_sched_barrier(0);             // no next-stage hoists above
    __builtin_amdgcn_s_barrier();                  // reads done -> buf reusable
    cur ^= 1;
  }
}

// ---------------------------------------------------------------------------
// 64x128 GEMM mainloop v4 (r6-verified, unchanged): for proj_mm.
// ---------------------------------------------------------------------------
__device__ __forceinline__ void gemm64x128(
    const u16* __restrict__ A, const u16* __restrict__ B, int K,
    int m0, int n0, u16* As, u16* Bs, floatx4 acc[2][4]) {
  const int t = threadIdx.x;
  const int w = t >> 6, lane = t & 63;
  const int wm = w & 1, wn = w >> 1;
  const int quad = lane >> 4, l16 = lane & 15;
  const int r = t >> 2;                            // staging row 0..63
  const int c = ((t & 3) ^ ((t >> 3) & 3)) * 8;    // swizzled source block
  const int rs = (quad ^ ((l16 >> 1) & 3)) * 8;    // read-side slot

  const u16* ap  = A + (size_t)(m0 + r) * K + c;
  const u16* bp0 = B + (size_t)(n0 + r) * K + c;
  const u16* bp1 = B + (size_t)(n0 + 64 + r) * K + c;
  u16* const al  = As + w * 512;                   // wave-uniform LDS bases
  u16* const bl0 = Bs + w * 512;
  u16* const bl1 = Bs + 2048 + w * 512;

#pragma unroll
  for (int i = 0; i < 2; ++i)
#pragma unroll
    for (int j = 0; j < 4; ++j) acc[i][j] = 0.f;

  // prologue: tile 0 -> buffer 0
  async16(ap,  al);
  async16(bp0, bl0);
  async16(bp1, bl1);

  int cur = 0;
  for (int k0 = 0; k0 < K; k0 += 32) {
    if (k0 + 32 < K) {
      const int nb = cur ^ 1;
      async16(ap  + k0 + 32, al  + nb * 2048);
      async16(bp0 + k0 + 32, bl0 + nb * 4096);
      async16(bp1 + k0 + 32, bl1 + nb * 4096);
      __builtin_amdgcn_sched_barrier(0);           // stages precede the wait
      asm volatile("s_waitcnt vmcnt(3)");          // prev tile done; 3 in flight
    } else {
      asm volatile("s_waitcnt vmcnt(0)");          // epilogue drain
    }
    __builtin_amdgcn_s_barrier();                  // all waves' deposits visible
    __builtin_amdgcn_sched_barrier(0);             // no ds_read hoists above

    short8 af[2], bfr[4];
#pragma unroll
    for (int i = 0; i < 2; ++i)
      af[i]  = *(const short8*)(As + cur * 2048 +
                                (wm * 32 + i * 16 + l16) * 32 + rs);
#pragma unroll
    for (int j = 0; j < 4; ++j)
      bfr[j] = *(const short8*)(Bs + cur * 4096 +
                                (wn * 64 + j * 16 + l16) * 32 + rs);
#pragma unroll
    for (int i = 0; i < 2; ++i)
#pragma unroll
      for (int j = 0; j < 4; ++j)
        acc[i][j] = mfma16(af[i], bfr[j], acc[i][j]);

    __builtin_amdgcn_sched_barrier(0);             // no next-stage hoists above
    __builtin_amdgcn_s_barrier();                  // reads done -> buf reusable
    cur ^= 1;
  }
}

// ---------------------------------------------------------------------------
// QKV GEMM (r7-verified, unchanged): Grid (8, 32, 3) = 768 blocks.
// ---------------------------------------------------------------------------
__global__ __launch_bounds__(256, 4) void qkv_mm(
    const u16* __restrict__ xb, const u16* __restrict__ Wb,
    const float* __restrict__ bq, const float* __restrict__ bk,
    const float* __restrict__ bv,
    u16* __restrict__ Q, u16* __restrict__ K_, u16* __restrict__ Vt) {
  __shared__ __align__(16) u16 As[8192], Bs[8192];
  const int z = blockIdx.z;
  const u16* W = Wb + ((size_t)z << 20);
  const float* bias = (z == 0) ? bq : (z == 1) ? bk : bv;
  const int m0 = blockIdx.y * 128, n0 = blockIdx.x * 128;

  floatx4 acc[4][4];
  gemm128d(xb, W, Ec, m0, n0, As, Bs, acc);

  const int t = threadIdx.x, w = t >> 6, lane = t & 63;
  const int wm = w & 1, wn = w >> 1, quad = lane >> 4, l16 = lane & 15;
#pragma unroll
  for (int i = 0; i < 4; ++i)
#pragma unroll
    for (int j = 0; j < 4; ++j)
#pragma unroll
      for (int rr = 0; rr < 4; ++rr) {
        const int row = m0 + wm * 64 + i * 16 + quad * 4 + rr;
        const int col = n0 + wn * 64 + j * 16 + l16;
        float v = acc[i][j][rr] + bias[col];
        if (z == 0) v *= QSCALE;
        const int bb = row >> 11, s = row & (Sc - 1);
        const int h = col >> 6, d = col & (Dc - 1), bh = bb * Hc + h;
        if (z < 2) ((z == 0) ? Q : K_)[((size_t)bh * Sc + s) * Dc + d] = f2b(v);
        else {
          const int sp = (s & ~31) | ((s & 12) << 1) | ((s & 16) >> 2) | (s & 3);
          Vt[((size_t)bh * Dc + d) * Sc + sp] = f2b(v);
        }
      }
}

// ---------------------------------------------------------------------------
// Output projection (r6-verified, unchanged): Grid (8, 64) = 512 = 2/CU.
// ---------------------------------------------------------------------------
__global__ __launch_bounds__(256, 6) void proj_mm(
    const u16* __restrict__ O, const u16* __restrict__ Wob,
    const float* __restrict__ bias, float* __restrict__ out) {
  __shared__ __align__(16) u16 As[4096], Bs[8192];
  const int m0 = blockIdx.y * 64, n0 = blockIdx.x * 128;

  floatx4 acc[2][4];
  gemm64x128(O, Wob, Ec, m0, n0, As, Bs, acc);

  const int t = threadIdx.x, w = t >> 6, lane = t & 63;
  const int wm = w & 1, wn = w >> 1, quad = lane >> 4, l16 = lane & 15;
#pragma unroll
  for (int i = 0; i < 2; ++i)
#pragma unroll
    for (int j = 0; j < 4; ++j)
#pragma unroll
      for (int rr = 0; rr < 4; ++rr) {
        const int row = m0 + wm * 32 + i * 16 + quad * 4 + rr;
        const int col = n0 + wn * 64 + j * 16 + l16;
        out[(size_t)row * Ec + col] = acc[i][j][rr] + bias[col];
      }
}

// ---------------------------------------------------------------------------
// Flash attention v9: 2 q-GROUPS per wave (32 q-rows) — every K/V fragment
// ds_read now feeds TWO MFMAs, halving per-CU LDS-read and staging traffic
// per unit compute (the same arithmetic-intensity lever that fixed qkv in r7;
// attn was plateaued 46-52us across r1/r8/r9 structural variants).
// Block = 4 waves x 32 rows = 128 q-rows; grid 512 (16 qt x 32 bh) = 2
// blocks/CU; pairing id<->id+256 as (qt, 15-qt) -> 17-iter makespan/CU.
// Counted-vmcnt dbuf K/V staging (r6-verified structure; per-iter compute
// here is ~3x r8's, ample to hide vmcnt(8)). Two independent QK->softmax->PV
// chains per wave add intra-wave ILP. LDS 2x(16K+16K)=64KB -> 2 blocks/CU.
// ---------------------------------------------------------------------------
__global__ __launch_bounds__(256, 2) void attn_kernel(
    const u16* __restrict__ Q, const u16* __restrict__ K,
    const u16* __restrict__ Vt, u16* __restrict__ O) {
  const int id = blockIdx.x;                 // 0..511
  int qt, bh;
  if (id < 256) { qt = id & 15;        bh = id >> 4; }              // bh 0..15
  else          { qt = 15 - (id & 15); bh = 16 + ((id - 256) >> 4); } // 16..31
  const int q0 = qt * 128;
  const int bb = bh >> 4, h = bh & 15;

  const u16* Qh = Q  + (size_t)bh * Sc * Dc;
  const u16* Kh = K  + (size_t)bh * Sc * Dc;
  const u16* Vh = Vt + (size_t)bh * Dc * Sc;

  const int t = threadIdx.x;
  const int w = t >> 6, lane = t & 63;
  const int quad = lane >> 4, l16 = lane & 15;

  __shared__ __align__(16) u16 Ks[16384];  // dbuf: 2 x [2 st][64key][64d]
  __shared__ __align__(16) u16 Vs[16384];  // dbuf: 2 x [2 st][64d][64key(sigma)]

  const int sr = w * 8 + (lane >> 3);        // staging row within 32-row half
  const int sb = (lane & 7) ^ (lane >> 3);   // staging source 16B block
  const int swz = l16 & 7;                   // read-side swizzle

  // Q fragments for both q-groups (rows q0 + gq*64 + w*16 + l16).
  short8 aq[2][2];
#pragma unroll
  for (int gq = 0; gq < 2; ++gq) {
    const u16* qp = Qh + (size_t)(q0 + gq * 64 + w * 16 + l16) * Dc;
    aq[gq][0] = ld8(qp + quad * 8);
    aq[gq][1] = ld8(qp + 32 + quad * 8);
  }

  float   lrow[2] = {0.f, 0.f};
  floatx4 oacc[2][4];
#pragma unroll
  for (int gq = 0; gq < 2; ++gq)
#pragma unroll
    for (int dt = 0; dt < 4; ++dt) oacc[gq][dt] = 0.f;

  // stage 128 keys of K and V^T for key-offset kt_ into buffer buf_
#define ATTN_STAGE(kt_, buf_)                                                  \
  {                                                                            \
    _Pragma("unroll")                                                          \
    for (int st = 0; st < 2; ++st)                                             \
      _Pragma("unroll")                                                        \
      for (int it = 0; it < 2; ++it) {                                         \
        const int r_ = it * 32 + sr;                                           \
        async16(Kh + (size_t)((kt_) + st * 64 + r_) * Dc + sb * 8,             \
                Ks + (buf_)*8192 + st * 4096 + it * 2048 + w * 512);           \
        async16(Vh + (size_t)r_ * Sc + (kt_) + st * 64 + sb * 8,               \
                Vs + (buf_)*8192 + st * 4096 + it * 2048 + w * 512);           \
      }                                                                        \
  }

  ATTN_STAGE(0, 0);
  int cur = 0;
  for (int kt = 0; kt <= q0; kt += 128) {
    if (kt < q0) {
      ATTN_STAGE(kt + 128, cur ^ 1);
      __builtin_amdgcn_sched_barrier(0);           // stages precede the wait
      asm volatile("s_waitcnt vmcnt(8)");          // prev tile's 8 done
    } else {
      asm volatile("s_waitcnt vmcnt(0)");          // last tile drain
    }
    __builtin_amdgcn_s_barrier();                  // all waves' deposits visible
    __builtin_amdgcn_sched_barrier(0);             // no ds_read hoists above

    // ---- S^T = K Q^T, both groups share every K fragment read ----
    floatx4 sacc[2][8];
#pragma unroll
    for (int gq = 0; gq < 2; ++gq)
#pragma unroll
      for (int g = 0; g < 8; ++g) sacc[gq][g] = 0.f;
    __builtin_amdgcn_s_setprio(1);
#pragma unroll
    for (int ks = 0; ks < 2; ++ks) {
#pragma unroll
      for (int g = 0; g < 8; ++g) {
        const short8 a = *(const short8*)(
            Ks + cur * 8192 + (g >> 2) * 4096 + ((g & 3) * 16 + l16) * 64 +
            (((ks * 4 + quad) ^ swz) * 8));
        sacc[0][g] = mfma16(a, aq[0][ks], sacc[0][g]);
        sacc[1][g] = mfma16(a, aq[1][ks], sacc[1][g]);
      }
    }
    __builtin_amdgcn_s_setprio(0);

    // ---- fixed-norm softmax in registers: p = exp2(s); masked -> 0 ----
    const bool diag = (kt == q0);                  // only the last tile masks
#pragma unroll
    for (int gq = 0; gq < 2; ++gq) {
      const int thr = gq * 64 + w * 16 + l16 - 4 * quad;  // mask iff 16g+r > thr
#pragma unroll
      for (int g = 0; g < 8; ++g)
#pragma unroll
        for (int r = 0; r < 4; ++r) {
          float pv = exp2f(sacc[gq][g][r]);  // bounded: |s| << 127 structurally
          if (diag && (16 * g + r > thr)) pv = 0.f;
          lrow[gq] += pv;
          sacc[gq][g][r] = pv;
        }
    }

    // ---- pack P to bf16 A-frags in-register (keys sigma-match V) ----
    short8 pa[2][4];
#pragma unroll
    for (int gq = 0; gq < 2; ++gq)
#pragma unroll
      for (int c = 0; c < 4; ++c) {
        intx4 wd;
        wd[0] = cvt_pk(sacc[gq][2 * c][0],     sacc[gq][2 * c][1]);
        wd[1] = cvt_pk(sacc[gq][2 * c][2],     sacc[gq][2 * c][3]);
        wd[2] = cvt_pk(sacc[gq][2 * c + 1][0], sacc[gq][2 * c + 1][1]);
        wd[3] = cvt_pk(sacc[gq][2 * c + 1][2], sacc[gq][2 * c + 1][3]);
        pa[gq][c] = __builtin_bit_cast(short8, wd);
      }

    // ---- O += P V, both groups share every V fragment read ----
    __builtin_amdgcn_s_setprio(1);
#pragma unroll
    for (int c = 0; c < 4; ++c) {
      const int st = c >> 1, kcl = c & 1;
#pragma unroll
      for (int dt = 0; dt < 4; ++dt) {
        const short8 b = *(const short8*)(
            Vs + cur * 8192 + st * 4096 + (dt * 16 + l16) * 64 +
            (((kcl * 4 + quad) ^ swz) * 8));
        oacc[0][dt] = mfma16(pa[0][c], b, oacc[0][dt]);
        oacc[1][dt] = mfma16(pa[1][c], b, oacc[1][dt]);
      }
    }
    __builtin_amdgcn_s_setprio(0);

    __builtin_amdgcn_sched_barrier(0);             // no next-stage hoists above
    __builtin_amdgcn_s_barrier();                  // reads done -> buf reusable
    cur ^= 1;
  }

  // ---- final row-sum reduction across the 4 quads, then normalize ----
#pragma unroll
  for (int gq = 0; gq < 2; ++gq) {
    lrow[gq] += __shfl_xor(lrow[gq], 16);
    lrow[gq] += __shfl_xor(lrow[gq], 32);   // every lane: total for q-row l16
    float rs[4];
#pragma unroll
    for (int r = 0; r < 4; ++r)
      rs[r] = 1.f / __shfl(lrow[gq], quad * 4 + r, 16);
#pragma unroll
    for (int dt = 0; dt < 4; ++dt)
#pragma unroll
      for (int r = 0; r < 4; ++r) {
        const int qrow = q0 + gq * 64 + w * 16 + quad * 4 + r;
        O[((size_t)(bb * Sc + qrow)) * Ec + h * Dc + dt * 16 + l16] =
            f2b(oacc[gq][dt][r] * rs[r]);
      }
  }
}

// ---------------------------------------------------------------------------
extern "C" void kernel_launch(void* const* d_in, const int* in_sizes, int n_in,
                              void* d_out, int out_size, void* d_ws, size_t ws_size,
                              hipStream_t stream) {
  const float* x  = (const float*)d_in[0];
  // d_in[1] = causal mask (int32): applied analytically (tril)
  const float* Wq = (const float*)d_in[2];
  const float* bq = (const float*)d_in[3];
  const float* Wk = (const float*)d_in[4];
  const float* bk = (const float*)d_in[5];
  const float* Wv = (const float*)d_in[6];
  const float* bv = (const float*)d_in[7];
  const float* Wo = (const float*)d_in[8];
  const float* bo = (const float*)d_in[9];

  const size_t MiE = (size_t)Mc * Ec;      // 4 Mi elements
  u16* Q  = (u16*)d_ws;                    //  8 MB
  u16* K  = Q  + MiE;                      //  8 MB
  u16* Vt = K  + MiE;                      //  8 MB
  u16* O  = Vt + MiE;                      //  8 MB
  u16* xb = O  + MiE;                      //  8 MB   (cvt dst base)
  u16* Wb = xb + MiE;                      //  8 MB   (Wq|Wk|Wv|Wo bf16)
  u16* Wob = Wb + ((size_t)3 << 20);

  cvt_kernel<<<8192, 256, 0, stream>>>(x, Wq, Wk, Wv, Wo, xb);
  qkv_mm<<<dim3(Ec / 128, Mc / 128, 3), 256, 0, stream>>>(
      xb, Wb, bq, bk, bv, Q, K, Vt);
  attn_kernel<<<512, 256, 0, stream>>>(Q, K, Vt, O);
  proj_mm<<<dim3(Ec / 128, Mc / 64), 256, 0, stream>>>(O, Wob, bo, (float*)d_out);
}

// Round 12
// 198.035 us; speedup vs baseline: 1.0359x; 1.0359x over previous
//
#include <hip/hip_runtime.h>

typedef unsigned short u16;
typedef __attribute__((ext_vector_type(8))) __bf16 bf16x8;
typedef __attribute__((ext_vector_type(8))) short  short8;
typedef __attribute__((ext_vector_type(4))) short  short4v;
typedef __attribute__((ext_vector_type(4))) float  floatx4;
typedef __attribute__((ext_vector_type(4))) int    intx4;
typedef __attribute__((ext_vector_type(2))) int    intx2;

constexpr int Bc = 2, Sc = 2048, Ec = 1024, Hc = 16, Dc = 64;
constexpr int Mc = Bc * Sc;  // 4096

#define QSCALE  0.18033688011112042f  // 0.125 * log2(e): scores in exp2 domain

__device__ __forceinline__ u16 f2b(float f) {          // RTNE
  union { float f; unsigned u; } c; c.f = f;
  unsigned u = c.u;
  return (u16)((u + 0x7fffu + ((u >> 16) & 1u)) >> 16);
}
__device__ __forceinline__ short8 ld8(const u16* p) { return *(const short8*)p; }

// packed f32x2 -> bf16x2 (RTNE), 1 VALU op [T12 recipe; no builtin on gfx950]
__device__ __forceinline__ int cvt_pk(float lo, float hi) {
  int r;
  asm("v_cvt_pk_bf16_f32 %0, %1, %2" : "=v"(r) : "v"(lo), "v"(hi));
  return r;
}

__device__ __forceinline__ floatx4 mfma16(short8 a, short8 b, floatx4 c) {
  return __builtin_amdgcn_mfma_f32_16x16x32_bf16(
      __builtin_bit_cast(bf16x8, a), __builtin_bit_cast(bf16x8, b), c, 0, 0, 0);
}

// async global->LDS, 16B/lane; LDS ptr is the wave-uniform base (HW deposits
// at base + lane*16). [m97/m104 pattern]
__device__ __forceinline__ void async16(const u16* g, u16* l) {
  __builtin_amdgcn_global_load_lds(
      (const __attribute__((address_space(1))) void*)g,
      (__attribute__((address_space(3))) void*)l, 16, 0, 0);
}

// ---------------------------------------------------------------------------
// fp32 -> bf16 bulk convert: dst = [xb (4Mi) | Wq | Wk | Wv | Wo (1Mi each)].
// ---------------------------------------------------------------------------
__global__ __launch_bounds__(256) void cvt_kernel(
    const float* __restrict__ x,  const float* __restrict__ Wq,
    const float* __restrict__ Wk, const float* __restrict__ Wv,
    const float* __restrict__ Wo, u16* __restrict__ dst) {
  const size_t i = ((size_t)blockIdx.x * 256 + threadIdx.x) * 4;
  const int seg = (int)(i >> 20);
  const float* src;
  size_t off;
  if (seg < 4)       { src = x;  off = i; }
  else if (seg == 4) { src = Wq; off = i - ((size_t)4 << 20); }
  else if (seg == 5) { src = Wk; off = i - ((size_t)5 << 20); }
  else if (seg == 6) { src = Wv; off = i - ((size_t)6 << 20); }
  else               { src = Wo; off = i - ((size_t)7 << 20); }
  floatx4 v = *(const floatx4*)(src + off);
  intx2 o;
  o[0] = cvt_pk(v[0], v[1]);
  o[1] = cvt_pk(v[2], v[3]);
  *(intx2*)(dst + i) = o;
}

// ---------------------------------------------------------------------------
// 128x128 GEMM mainloop v5 (r7-verified): counted-vmcnt double-buffer.
// ---------------------------------------------------------------------------
__device__ __forceinline__ void gemm128d(
    const u16* __restrict__ A, const u16* __restrict__ B, int K,
    int m0, int n0, u16* As, u16* Bs, floatx4 acc[4][4]) {
  const int t = threadIdx.x;
  const int w = t >> 6, lane = t & 63;
  const int wm = w & 1, wn = w >> 1;
  const int quad = lane >> 4, l16 = lane & 15;
  const int r = t >> 2;                            // staging row 0..63
  const int c = ((t & 3) ^ ((t >> 3) & 3)) * 8;    // swizzled source block
  const int rs = (quad ^ ((l16 >> 1) & 3)) * 8;    // read-side slot

  const u16* ap0 = A + (size_t)(m0 + r) * K + c;
  const u16* ap1 = A + (size_t)(m0 + 64 + r) * K + c;
  const u16* bp0 = B + (size_t)(n0 + r) * K + c;
  const u16* bp1 = B + (size_t)(n0 + 64 + r) * K + c;
  u16* const al0 = As + w * 512;                   // wave-uniform LDS bases
  u16* const al1 = As + 2048 + w * 512;
  u16* const bl0 = Bs + w * 512;
  u16* const bl1 = Bs + 2048 + w * 512;

#pragma unroll
  for (int i = 0; i < 4; ++i)
#pragma unroll
    for (int j = 0; j < 4; ++j) acc[i][j] = 0.f;

  // prologue: tile 0 -> buffer 0
  async16(ap0, al0);
  async16(ap1, al1);
  async16(bp0, bl0);
  async16(bp1, bl1);

  int cur = 0;
  for (int k0 = 0; k0 < K; k0 += 32) {
    if (k0 + 32 < K) {
      const int nb = cur ^ 1;
      async16(ap0 + k0 + 32, al0 + nb * 4096);
      async16(ap1 + k0 + 32, al1 + nb * 4096);
      async16(bp0 + k0 + 32, bl0 + nb * 4096);
      async16(bp1 + k0 + 32, bl1 + nb * 4096);
      __builtin_amdgcn_sched_barrier(0);           // stages precede the wait
      asm volatile("s_waitcnt vmcnt(4)");          // prev tile done; 4 in flight
    } else {
      asm volatile("s_waitcnt vmcnt(0)");          // epilogue drain
    }
    __builtin_amdgcn_s_barrier();                  // all waves' deposits visible
    __builtin_amdgcn_sched_barrier(0);             // no ds_read hoists above

    short8 af[4], bfr[4];
#pragma unroll
    for (int i = 0; i < 4; ++i)
      af[i]  = *(const short8*)(As + cur * 4096 +
                                (wm * 64 + i * 16 + l16) * 32 + rs);
#pragma unroll
    for (int j = 0; j < 4; ++j)
      bfr[j] = *(const short8*)(Bs + cur * 4096 +
                                (wn * 64 + j * 16 + l16) * 32 + rs);
#pragma unroll
    for (int i = 0; i < 4; ++i)
#pragma unroll
      for (int j = 0; j < 4; ++j)
        acc[i][j] = mfma16(af[i], bfr[j], acc[i][j]);

    __builtin_amdgcn_sched_barrier(0);             // no next-stage hoists above
    __builtin_amdgcn_s_barrier();                  // reads done -> buf reusable
    cur ^= 1;
  }
}

// ---------------------------------------------------------------------------
// 64x128 GEMM mainloop v4 (r6-verified, unchanged): for proj_mm.
// ---------------------------------------------------------------------------
__device__ __forceinline__ void gemm64x128(
    const u16* __restrict__ A, const u16* __restrict__ B, int K,
    int m0, int n0, u16* As, u16* Bs, floatx4 acc[2][4]) {
  const int t = threadIdx.x;
  const int w = t >> 6, lane = t & 63;
  const int wm = w & 1, wn = w >> 1;
  const int quad = lane >> 4, l16 = lane & 15;
  const int r = t >> 2;                            // staging row 0..63
  const int c = ((t & 3) ^ ((t >> 3) & 3)) * 8;    // swizzled source block
  const int rs = (quad ^ ((l16 >> 1) & 3)) * 8;    // read-side slot

  const u16* ap  = A + (size_t)(m0 + r) * K + c;
  const u16* bp0 = B + (size_t)(n0 + r) * K + c;
  const u16* bp1 = B + (size_t)(n0 + 64 + r) * K + c;
  u16* const al  = As + w * 512;                   // wave-uniform LDS bases
  u16* const bl0 = Bs + w * 512;
  u16* const bl1 = Bs + 2048 + w * 512;

#pragma unroll
  for (int i = 0; i < 2; ++i)
#pragma unroll
    for (int j = 0; j < 4; ++j) acc[i][j] = 0.f;

  // prologue: tile 0 -> buffer 0
  async16(ap,  al);
  async16(bp0, bl0);
  async16(bp1, bl1);

  int cur = 0;
  for (int k0 = 0; k0 < K; k0 += 32) {
    if (k0 + 32 < K) {
      const int nb = cur ^ 1;
      async16(ap  + k0 + 32, al  + nb * 2048);
      async16(bp0 + k0 + 32, bl0 + nb * 4096);
      async16(bp1 + k0 + 32, bl1 + nb * 4096);
      __builtin_amdgcn_sched_barrier(0);           // stages precede the wait
      asm volatile("s_waitcnt vmcnt(3)");          // prev tile done; 3 in flight
    } else {
      asm volatile("s_waitcnt vmcnt(0)");          // epilogue drain
    }
    __builtin_amdgcn_s_barrier();                  // all waves' deposits visible
    __builtin_amdgcn_sched_barrier(0);             // no ds_read hoists above

    short8 af[2], bfr[4];
#pragma unroll
    for (int i = 0; i < 2; ++i)
      af[i]  = *(const short8*)(As + cur * 2048 +
                                (wm * 32 + i * 16 + l16) * 32 + rs);
#pragma unroll
    for (int j = 0; j < 4; ++j)
      bfr[j] = *(const short8*)(Bs + cur * 4096 +
                                (wn * 64 + j * 16 + l16) * 32 + rs);
#pragma unroll
    for (int i = 0; i < 2; ++i)
#pragma unroll
      for (int j = 0; j < 4; ++j)
        acc[i][j] = mfma16(af[i], bfr[j], acc[i][j]);

    __builtin_amdgcn_sched_barrier(0);             // no next-stage hoists above
    __builtin_amdgcn_s_barrier();                  // reads done -> buf reusable
    cur ^= 1;
  }
}

// ---------------------------------------------------------------------------
// QKV GEMM (r7-verified, unchanged): Grid (8, 32, 3) = 768 blocks.
// ---------------------------------------------------------------------------
__global__ __launch_bounds__(256, 4) void qkv_mm(
    const u16* __restrict__ xb, const u16* __restrict__ Wb,
    const float* __restrict__ bq, const float* __restrict__ bk,
    const float* __restrict__ bv,
    u16* __restrict__ Q, u16* __restrict__ K_, u16* __restrict__ Vt) {
  __shared__ __align__(16) u16 As[8192], Bs[8192];
  const int z = blockIdx.z;
  const u16* W = Wb + ((size_t)z << 20);
  const float* bias = (z == 0) ? bq : (z == 1) ? bk : bv;
  const int m0 = blockIdx.y * 128, n0 = blockIdx.x * 128;

  floatx4 acc[4][4];
  gemm128d(xb, W, Ec, m0, n0, As, Bs, acc);

  const int t = threadIdx.x, w = t >> 6, lane = t & 63;
  const int wm = w & 1, wn = w >> 1, quad = lane >> 4, l16 = lane & 15;
#pragma unroll
  for (int i = 0; i < 4; ++i)
#pragma unroll
    for (int j = 0; j < 4; ++j)
#pragma unroll
      for (int rr = 0; rr < 4; ++rr) {
        const int row = m0 + wm * 64 + i * 16 + quad * 4 + rr;
        const int col = n0 + wn * 64 + j * 16 + l16;
        float v = acc[i][j][rr] + bias[col];
        if (z == 0) v *= QSCALE;
        const int bb = row >> 11, s = row & (Sc - 1);
        const int h = col >> 6, d = col & (Dc - 1), bh = bb * Hc + h;
        if (z < 2) ((z == 0) ? Q : K_)[((size_t)bh * Sc + s) * Dc + d] = f2b(v);
        else {
          const int sp = (s & ~31) | ((s & 12) << 1) | ((s & 16) >> 2) | (s & 3);
          Vt[((size_t)bh * Dc + d) * Sc + sp] = f2b(v);
        }
      }
}

// ---------------------------------------------------------------------------
// Output projection (r6-verified, unchanged): Grid (8, 64) = 512 = 2/CU.
// ---------------------------------------------------------------------------
__global__ __launch_bounds__(256, 6) void proj_mm(
    const u16* __restrict__ O, const u16* __restrict__ Wob,
    const float* __restrict__ bias, float* __restrict__ out) {
  __shared__ __align__(16) u16 As[4096], Bs[8192];
  const int m0 = blockIdx.y * 64, n0 = blockIdx.x * 128;

  floatx4 acc[2][4];
  gemm64x128(O, Wob, Ec, m0, n0, As, Bs, acc);

  const int t = threadIdx.x, w = t >> 6, lane = t & 63;
  const int wm = w & 1, wn = w >> 1, quad = lane >> 4, l16 = lane & 15;
#pragma unroll
  for (int i = 0; i < 2; ++i)
#pragma unroll
    for (int j = 0; j < 4; ++j)
#pragma unroll
      for (int rr = 0; rr < 4; ++rr) {
        const int row = m0 + wm * 32 + i * 16 + quad * 4 + rr;
        const int col = n0 + wn * 64 + j * 16 + l16;
        out[(size_t)row * Ec + col] = acc[i][j][rr] + bias[col];
      }
}

// ---------------------------------------------------------------------------
// Flash attention v10 (launch-FIXED): r7-proven structure (4-wave blocks,
// 128-key tiles, single-buffer + syncthreads, GRID dim3(256,4) — the mapping
// below requires blockIdx.x in 0..255 and blockIdx.y in 0..3; r11's failure
// was launching this body with dim3(32,32)), plus two surgical VALU cuts:
//  (1) ones-MFMA row-sum: lacc = mfma(pa[c], ones, lacc) accumulates the
//      softmax denominator on the idle matrix pipe (4 MFMA/iter) instead of
//      32 scalar VALU adds/iter. With B = all-ones, D[i][j] = rowsum(A[i])
//      independent of operand layout/sigma; D-row indexing (quad*4+r)
//      matches oacc's, so the epilogue needs NO cross-lane shuffles.
//  (2) T5 s_setprio(1) around both MFMA clusters (m191: +4-7% on attn with
//      desynced multi-block CUs — r7's geometry).
// ---------------------------------------------------------------------------
__global__ __launch_bounds__(256, 4) void attn_kernel(
    const u16* __restrict__ Q, const u16* __restrict__ K,
    const u16* __restrict__ Vt, u16* __restrict__ O) {
  // balanced pair mapping: per-CU qt multiset {v, 31-v, (v+8)&31, 31-((v+8)&31)}
  const int v  = blockIdx.x & 31, g8 = blockIdx.x >> 5, kk = blockIdx.y;
  const int q1 = (kk & 2) ? ((v + 8) & 31) : v;
  const int qt = (kk & 1) ? (31 - q1) : q1;
  const int q0 = qt * 64;
  const int bh = kk * 8 + g8;
  const int bb = bh >> 4, h = bh & 15;

  const u16* Qh = Q  + (size_t)bh * Sc * Dc;
  const u16* Kh = K  + (size_t)bh * Sc * Dc;
  const u16* Vh = Vt + (size_t)bh * Dc * Sc;

  const int t = threadIdx.x;
  const int w = t >> 6, lane = t & 63;
  const int quad = lane >> 4, l16 = lane & 15;

  __shared__ __align__(16) u16 Ks[8192];   // 2 sub-tiles [64key][64d], swizzled
  __shared__ __align__(16) u16 Vs[8192];   // 2 sub-tiles [64d][64key(sigma)], swizzled

  const int sr = w * 8 + (lane >> 3);        // staging row within 32-row half
  const int sb = (lane & 7) ^ (lane >> 3);   // staging source 16B block
  const int swz = l16 & 7;                   // read-side swizzle

  // Q fragments: loop-invariant registers (Q pre-scaled by QSCALE).
  // Used as the MFMA *B* operand: col = l16 = this lane's q-row.
  const u16* qrow_p = Qh + (size_t)(q0 + w * 16 + l16) * Dc;
  const short8 aq0 = ld8(qrow_p + quad * 8);
  const short8 aq1 = ld8(qrow_p + 32 + quad * 8);

  // all-ones bf16 B-operand for the denominator MFMA
  short8 bone;
#pragma unroll
  for (int j = 0; j < 8; ++j) bone[j] = (short)0x3F80;

  floatx4 lacc = 0.f;              // row-sum accumulator: lacc[r] = sum P[row]
  floatx4 oacc[4];
#pragma unroll
  for (int dt = 0; dt < 4; ++dt) oacc[dt] = 0.f;

  for (int kt = 0; kt <= q0; kt += 128) {
    // ---- stage 128 keys of K and V^T (always in-bounds: kt <= 1920) ----
#pragma unroll
    for (int st = 0; st < 2; ++st)
#pragma unroll
      for (int it = 0; it < 2; ++it) {
        const int r = it * 32 + sr;
        async16(Kh + (size_t)(kt + st * 64 + r) * Dc + sb * 8,
                Ks + st * 4096 + it * 2048 + w * 512);
        async16(Vh + (size_t)r * Sc + kt + st * 64 + sb * 8,
                Vs + st * 4096 + it * 2048 + w * 512);
      }
    __syncthreads();

    // ---- S^T = K Q^T : sacc[g][r] = score(key = kt+16g+4*quad+r, qrow l16) ----
    floatx4 sacc[8];
#pragma unroll
    for (int g = 0; g < 8; ++g) sacc[g] = 0.f;
    __builtin_amdgcn_s_setprio(1);
#pragma unroll
    for (int ks = 0; ks < 2; ++ks) {
      const short8 bq = ks ? aq1 : aq0;
#pragma unroll
      for (int g = 0; g < 8; ++g) {
        const short8 a = *(const short8*)(
            Ks + (g >> 2) * 4096 + ((g & 3) * 16 + l16) * 64 +
            (((ks * 4 + quad) ^ swz) * 8));
        sacc[g] = mfma16(a, bq, sacc[g]);
      }
    }
    __builtin_amdgcn_s_setprio(0);

    // ---- fixed-norm softmax in registers: p = exp2(s); masked -> 0 ----
    const bool diag = (kt + 128 > q0);
    const int thr = q0 + w * 16 + l16 - kt - 4 * quad;  // mask iff 16g+r > thr
#pragma unroll
    for (int g = 0; g < 8; ++g)
#pragma unroll
      for (int r = 0; r < 4; ++r) {
        float pv = exp2f(sacc[g][r]);   // bounded: |s| << 127 structurally
        if (diag && (16 * g + r > thr)) pv = 0.f;
        sacc[g][r] = pv;                // NOTE: no scalar row-sum adds here
      }

    // ---- pack P to bf16 A-frags entirely in-register (keys sigma-match V) ----
    short8 pa[4];
#pragma unroll
    for (int c = 0; c < 4; ++c) {
      intx4 wd;
      wd[0] = cvt_pk(sacc[2 * c][0],     sacc[2 * c][1]);
      wd[1] = cvt_pk(sacc[2 * c][2],     sacc[2 * c][3]);
      wd[2] = cvt_pk(sacc[2 * c + 1][0], sacc[2 * c + 1][1]);
      wd[3] = cvt_pk(sacc[2 * c + 1][2], sacc[2 * c + 1][3]);
      pa[c] = __builtin_bit_cast(short8, wd);
    }

    // ---- O += P V (and denominator += P 1) on the matrix pipe ----
    __builtin_amdgcn_s_setprio(1);
#pragma unroll
    for (int c = 0; c < 4; ++c) {
      const int st = c >> 1, kcl = c & 1;
      lacc = mfma16(pa[c], bone, lacc);            // row-sum of this key chunk
#pragma unroll
      for (int dt = 0; dt < 4; ++dt) {
        const short8 b = *(const short8*)(
            Vs + st * 4096 + (dt * 16 + l16) * 64 +
            (((kcl * 4 + quad) ^ swz) * 8));
        oacc[dt] = mfma16(pa[c], b, oacc[dt]);
      }
    }
    __builtin_amdgcn_s_setprio(0);
    __syncthreads();   // protect Ks/Vs before next tile's staging
  }

  // ---- normalize: lacc[r] IS the row total for qrow quad*4+r (no shuffles) --
  float rs[4];
#pragma unroll
  for (int r = 0; r < 4; ++r) rs[r] = 1.f / lacc[r];  // >0: diag key unmasked

#pragma unroll
  for (int dt = 0; dt < 4; ++dt) {
#pragma unroll
    for (int r = 0; r < 4; ++r) {
      const int qrow = q0 + w * 16 + quad * 4 + r;
      O[((size_t)(bb * Sc + qrow)) * Ec + h * Dc + dt * 16 + l16] =
          f2b(oacc[dt][r] * rs[r]);
    }
  }
}

// ---------------------------------------------------------------------------
extern "C" void kernel_launch(void* const* d_in, const int* in_sizes, int n_in,
                              void* d_out, int out_size, void* d_ws, size_t ws_size,
                              hipStream_t stream) {
  const float* x  = (const float*)d_in[0];
  // d_in[1] = causal mask (int32): applied analytically (tril)
  const float* Wq = (const float*)d_in[2];
  const float* bq = (const float*)d_in[3];
  const float* Wk = (const float*)d_in[4];
  const float* bk = (const float*)d_in[5];
  const float* Wv = (const float*)d_in[6];
  const float* bv = (const float*)d_in[7];
  const float* Wo = (const float*)d_in[8];
  const float* bo = (const float*)d_in[9];

  const size_t MiE = (size_t)Mc * Ec;      // 4 Mi elements
  u16* Q  = (u16*)d_ws;                    //  8 MB
  u16* K  = Q  + MiE;                      //  8 MB
  u16* Vt = K  + MiE;                      //  8 MB
  u16* O  = Vt + MiE;                      //  8 MB
  u16* xb = O  + MiE;                      //  8 MB   (cvt dst base)
  u16* Wb = xb + MiE;                      //  8 MB   (Wq|Wk|Wv|Wo bf16)
  u16* Wob = Wb + ((size_t)3 << 20);

  cvt_kernel<<<8192, 256, 0, stream>>>(x, Wq, Wk, Wv, Wo, xb);
  qkv_mm<<<dim3(Ec / 128, Mc / 128, 3), 256, 0, stream>>>(
      xb, Wb, bq, bk, bv, Q, K, Vt);
  attn_kernel<<<dim3(256, 4), 256, 0, stream>>>(Q, K, Vt, O);
  proj_mm<<<dim3(Ec / 128, Mc / 64), 256, 0, stream>>>(O, Wob, bo, (float*)d_out);
}